// Round 8
// baseline (192.990 us; speedup 1.0000x reference)
//
#include <hip/hip_runtime.h>
#include <hip/hip_bf16.h>

#define B_   512
#define C_   256
#define N_   81                 // tokens per batch (9x9)
#define M_   (B_ * N_)          // 41472
#define KNN  9

typedef __attribute__((ext_vector_type(8))) short short8;
typedef __attribute__((ext_vector_type(4))) float f32x4;

#define GLD16(g, l) __builtin_amdgcn_global_load_lds(                      \
    (const __attribute__((address_space(1))) void*)(g),                    \
    (__attribute__((address_space(3))) void*)(l), 16, 0, 0)

// ---------------------------------------------------------------- kernel A1
// Transpose/split, grid 4096 = (batch, 32-ch chunk). Writes the pre-swizzled
// 12288-B hl image per (b,ch) into hlbuf (rows 81..95 zeroed) + tokb hi rows.
// Image byte layout identical to r7's LDS hl, so knn_kernel's MFMA fragments
// are bit-identical. Pure memory-bound repack at full occupancy.
__global__ __launch_bounds__(256) void split_kernel(
    const float* __restrict__ x, ushort* __restrict__ tokb,
    char* __restrict__ hlbuf) {
  __shared__ __align__(16) float raw[32 * 81];   // 10368 B
  const int bid = blockIdx.x;
  const int b = bid >> 3, ch = bid & 7;
  const int tid = threadIdx.x;
  const float* src = x + (size_t)b * (C_ * N_) + ch * 32 * N_;
#pragma unroll
  for (int it = 0; it < 3; ++it) {
    int e4 = tid + it * 256;
    if (e4 < 648) *(f32x4*)&raw[e4 * 4] = *(const f32x4*)&src[e4 * 4];
  }
  char* dst = hlbuf + (size_t)bid * 12288;
  // zero pad rows 81..95 (480 u32)
  for (int p = tid; p < 480; p += 256)
    *(uint*)(dst + (81 + p / 32) * 128 + (p & 31) * 4) = 0u;
  __syncthreads();
  // transpose + hi/lo split: p = n*16 + q, channels c = 2q, 2q+1 (r7 verbatim)
#pragma unroll
  for (int it = 0; it < 6; ++it) {
    int p = tid + it * 256;
    if (p < 1296) {
      int n = p >> 4, q = p & 15;
      float v0 = raw[(2 * q) * N_ + n];
      float v1 = raw[(2 * q + 1) * N_ + n];
      __hip_bfloat16 h0 = __float2bfloat16(v0);
      __hip_bfloat16 h1 = __float2bfloat16(v1);
      float r0 = v0 - __bfloat162float(h0);
      float r1 = v1 - __bfloat162float(h1);
      __hip_bfloat16 g0 = __float2bfloat16(r0);
      __hip_bfloat16 g1 = __float2bfloat16(r1);
      uint hp = (uint)(*(ushort*)&h0) | ((uint)(*(ushort*)&h1) << 16);
      uint lp = (uint)(*(ushort*)&g0) | ((uint)(*(ushort*)&g1) << 16);
      int off = (((q >> 2) << 4) ^ (((n >> 1) & 3) << 4)) + ((q & 3) << 2);
      int hs = (n & 1) << 6;
      *(uint*)(dst + n * 128 + hs + off) = hp;
      *(uint*)(dst + n * 128 + (hs ^ 64) + off) = lp;
      *(uint*)&tokb[((size_t)(b * N_ + n)) * 256 + ch * 32 + 2 * q] = hp;
    }
  }
}

// ---------------------------------------------------------------- kernel A2
// Per batch: stream the 8 pre-swizzled hl chunks via double-buffered
// global_load_lds (counted vmcnt(3), raw s_barrier), 4-term MFMA gram
// (fragments bit-identical to r7), diag from G, 9-smallest selection.
__global__ __launch_bounds__(256) void knn_kernel(
    const char* __restrict__ hlbuf, int* __restrict__ knn_idx) {
  __shared__ __align__(16) char smem[31488];     // bufs 2x12288; G overlay
  __shared__ float sqv[96];
  const int b = blockIdx.x;
  const int tid = threadIdx.x;
  const int w = tid >> 6, lane = tid & 63;
  const int wr = w >> 1, wc = w & 1;              // 48x48 quadrant of G
  const int l15 = lane & 15;
  const int g16 = lane >> 4;                      // 16B k-group 0..3

  const char* srcb = hlbuf + (size_t)b * 8 * 12288;

  // prologue: stage chunk 0 -> buf0 (768 lane-slots, no divergence)
#pragma unroll
  for (int it = 0; it < 3; ++it) {
    int idx = it * 256 + tid;
    GLD16(srcb + idx * 16, smem + idx * 16);
  }

  f32x4 acc[3][3];
#pragma unroll
  for (int i = 0; i < 3; ++i)
#pragma unroll
    for (int j = 0; j < 3; ++j) acc[i][j] = {0.f, 0.f, 0.f, 0.f};

#pragma unroll
  for (int ch = 0; ch < 8; ++ch) {
    char* cur = smem + (ch & 1) * 12288;
    char* nxt = smem + ((ch + 1) & 1) * 12288;
    if (ch < 7) {
      const char* s2 = srcb + (size_t)(ch + 1) * 12288;
#pragma unroll
      for (int it = 0; it < 3; ++it) {
        int idx = it * 256 + tid;
        GLD16(s2 + idx * 16, nxt + idx * 16);
      }
      asm volatile("s_waitcnt vmcnt(3)" ::: "memory");   // cur's 3 done
    } else {
      asm volatile("s_waitcnt vmcnt(0)" ::: "memory");   // drain all
    }
    __builtin_amdgcn_s_barrier();
    __builtin_amdgcn_sched_barrier(0);
    // MFMA phase on cur (r7 addressing verbatim; terms hh, hl, lh, ll)
    short8 ah[3], al[3], bh[3], bl[3];
#pragma unroll
    for (int i = 0; i < 3; ++i) {
      int ra = wr * 48 + i * 16 + l15;
      int basea = ra * 128 + ((g16 << 4) ^ (((ra >> 1) & 3) << 4));
      int hsa = (ra & 1) << 6;
      ah[i] = *(const short8*)(cur + basea + hsa);
      al[i] = *(const short8*)(cur + basea + (hsa ^ 64));
      int rb = wc * 48 + i * 16 + l15;
      int baseb = rb * 128 + ((g16 << 4) ^ (((rb >> 1) & 3) << 4));
      int hsb = (rb & 1) << 6;
      bh[i] = *(const short8*)(cur + baseb + hsb);
      bl[i] = *(const short8*)(cur + baseb + (hsb ^ 64));
    }
#pragma unroll
    for (int i = 0; i < 3; ++i)
#pragma unroll
      for (int j = 0; j < 3; ++j) {
        acc[i][j] = __builtin_amdgcn_mfma_f32_16x16x32_bf16(
            ah[i], bh[j], acc[i][j], 0, 0, 0);
        acc[i][j] = __builtin_amdgcn_mfma_f32_16x16x32_bf16(
            ah[i], bl[j], acc[i][j], 0, 0, 0);
        acc[i][j] = __builtin_amdgcn_mfma_f32_16x16x32_bf16(
            al[i], bh[j], acc[i][j], 0, 0, 0);
        acc[i][j] = __builtin_amdgcn_mfma_f32_16x16x32_bf16(
            al[i], bl[j], acc[i][j], 0, 0, 0);
      }
    __builtin_amdgcn_sched_barrier(0);
    __builtin_amdgcn_s_barrier();   // reads done before next GLD overwrite
  }
  // G epilogue: [81][97] overlay. row=(lane>>4)*4+reg, col=lane&15 per frag
  float* G = (float*)smem;
#pragma unroll
  for (int i = 0; i < 3; ++i) {
    const int row0 = wr * 48 + i * 16 + ((lane >> 4) << 2);
#pragma unroll
    for (int j = 0; j < 3; ++j) {
      const int col = wc * 48 + j * 16 + l15;
#pragma unroll
      for (int reg = 0; reg < 4; ++reg) {
        const int row = row0 + reg;
        if (row < N_) G[row * 97 + col] = acc[i][j][reg];
      }
    }
  }
  __syncthreads();
  if (tid < N_) sqv[tid] = G[tid * 97 + tid];   // diag = |token|^2 (4-term)
  __syncthreads();
  if (tid < N_) {
    const int n = tid;
    const float sn = sqv[n];
    const float* grow = &G[n * 97];
    float bd[KNN]; int bi[KNN];
#pragma unroll
    for (int k = 0; k < KNN; ++k) { bd[k] = 3.4e38f; bi[k] = 0; }
    for (int m = 0; m < N_; ++m) {
      float d2 = sn + sqv[m] - 2.f * grow[m];
      float wv = bd[0]; int wi = 0;
#pragma unroll
      for (int k = 1; k < KNN; ++k) {
        bool g_ = bd[k] > wv;
        wv = g_ ? bd[k] : wv;
        wi = g_ ? k : wi;
      }
      bool repl = d2 < wv;
#pragma unroll
      for (int k = 0; k < KNN; ++k) {         // compile-time indices
        bool here = repl & (wi == k);
        bd[k] = here ? d2 : bd[k];
        bi[k] = here ? m : bi[k];
      }
    }
#pragma unroll
    for (int k = 0; k < KNN; ++k)
      knn_idx[((size_t)b * N_ + n) * KNN + k] = bi[k];
  }
}

// ---------------------------------------------------------------- kernel W
// Pack wq|wk|wv into bf16 [768][256], biases into fp32 [768].
__global__ __launch_bounds__(256) void pack_w_kernel(
    const float* __restrict__ wq, const float* __restrict__ bq,
    const float* __restrict__ wk, const float* __restrict__ bk,
    const float* __restrict__ wv, const float* __restrict__ bv,
    ushort* __restrict__ wcat, float* __restrict__ bcat) {
  const int j = blockIdx.x, c = threadIdx.x;
  const int sel = j >> 8, jr = j & 255;
  const float* W  = sel == 0 ? wq : (sel == 1 ? wk : wv);
  const float* Bb = sel == 0 ? bq : (sel == 1 ? bk : bv);
  __hip_bfloat16 h = __float2bfloat16(W[jr * 256 + c]);
  wcat[(size_t)j * 256 + c] = *(ushort*)&h;
  if (c == 0) bcat[j] = Bb[jr];
}

// ---------------------------------------------------------------- kernel B
// bf16 MFMA GEMM: qkv[M][768] = tok[M][256] @ wcat^T + bcat.
// 128x128 tile, BK=64, 4 waves (2x2), 4x4 frags of 16x16x32.
// T2 swizzle: LDS linear dest, pre-swizzled global src, swizzled ds_read.
__global__ __launch_bounds__(256) void qkv_mfma_kernel(
    const ushort* __restrict__ tokb, const ushort* __restrict__ wcat,
    const float* __restrict__ bcat, float* __restrict__ qkv) {
  __shared__ ushort At[128 * 64];   // 16 KB, row-major [r][k], swizzled
  __shared__ ushort Bt[128 * 64];   // 16 KB
  const int tid = threadIdx.x;
  const int m0 = blockIdx.x * 128;
  const int j0 = blockIdx.y * 128;
  const int w = tid >> 6, lane = tid & 63;
  const int wr = w >> 1, wc = w & 1;

  // staging: physical byte o -> logical col (o&127) ^ ((row&7)<<4)
  const char* pA[4]; const char* pB[4]; int oL[4];
#pragma unroll
  for (int it = 0; it < 4; ++it) {
    int o = (it * 256 + tid) * 16;
    int r = o >> 7, cp = o & 127;
    int cl = cp ^ ((r & 7) << 4);
    oL[it] = o;
    pA[it] = (const char*)tokb + ((size_t)(m0 + r) * 256) * 2 + cl;
    pB[it] = (const char*)wcat + ((size_t)(j0 + r) * 256) * 2 + cl;
  }

  f32x4 acc[4][4];
#pragma unroll
  for (int i = 0; i < 4; ++i)
#pragma unroll
    for (int j = 0; j < 4; ++j) acc[i][j] = {0.f, 0.f, 0.f, 0.f};

  const int l15 = lane & 15;
  const int sw = (lane & 7) << 4;          // read-side swizzle (row&7 == lane&7)
  const int kgrp = (lane >> 4) << 4;       // k-group byte offset within 64B half

  for (int k0 = 0; k0 < 256; k0 += 64) {
    __syncthreads();
#pragma unroll
    for (int it = 0; it < 4; ++it) {
      GLD16(pA[it] + k0 * 2, (char*)At + oL[it]);
      GLD16(pB[it] + k0 * 2, (char*)Bt + oL[it]);
    }
    __syncthreads();
#pragma unroll
    for (int kk = 0; kk < 2; ++kk) {
      const int cb = (kk * 64 + kgrp) ^ sw;
      short8 am[4], bn[4];
#pragma unroll
      for (int i = 0; i < 4; ++i) {
        const int ra = wr * 64 + i * 16 + l15;
        am[i] = *(const short8*)((const char*)At + ra * 128 + cb);
        const int rb = wc * 64 + i * 16 + l15;
        bn[i] = *(const short8*)((const char*)Bt + rb * 128 + cb);
      }
#pragma unroll
      for (int i = 0; i < 4; ++i)
#pragma unroll
        for (int j = 0; j < 4; ++j)
          acc[i][j] = __builtin_amdgcn_mfma_f32_16x16x32_bf16(
              am[i], bn[j], acc[i][j], 0, 0, 0);
    }
  }

  // epilogue: C[row][col], col=lane&15, row=(lane>>4)*4+reg
#pragma unroll
  for (int j = 0; j < 4; ++j) {
    const int colj = j0 + wc * 64 + j * 16 + l15;
    const float bs = bcat[colj];
#pragma unroll
    for (int i = 0; i < 4; ++i) {
      const int rowm = m0 + wr * 64 + i * 16 + ((lane >> 4) << 2);
#pragma unroll
      for (int reg = 0; reg < 4; ++reg)
        qkv[(size_t)(rowm + reg) * 768 + colj] = acc[i][j][reg] + bs;
    }
  }
}

// ---------------------------------------------------------------- kernel C
// One WAVE per token. 16 lanes per head, each lane owns 4 dims (float4).
// Score reduce = 4 shuffle rounds over 16 lanes. exp via v_exp_f32 (exp2).
// Writes output in place into the q-slot of qkv.
__global__ __launch_bounds__(256) void attn_kernel(
    const float* __restrict__ qkvc, const int* __restrict__ knn_idx,
    const float* __restrict__ a, float* __restrict__ qkv) {
  const int nwg = M_ / 4;                    // 10368 = 8 * 1296
  const int bid = blockIdx.x;
  const int swz = (bid & 7) * (nwg / 8) + (bid >> 3);  // XCD-contiguous
  const int w = threadIdx.x >> 6, lane = threadIdx.x & 63;
  const int m = swz * 4 + w;                 // this wave's token
  const int b = m / N_;
  const int bbase = b * N_;

  const f32x4 q4 = *(const f32x4*)&qkvc[(size_t)m * 768 + lane * 4];
  const f32x4 a4 = *(const f32x4*)&a[lane * 4];

  float sc[KNN];
  int nb[KNN];
#pragma unroll
  for (int k = 0; k < KNN; ++k) {
    int nbk = knn_idx[(size_t)m * KNN + k];
    nbk = __builtin_amdgcn_readfirstlane(nbk);
    nb[k] = nbk;
    const float* krow = qkvc + (size_t)(bbase + nbk) * 768 + 256;
    const f32x4 k4 = *(const f32x4*)&krow[lane * 4];
    float p = 0.f;
#pragma unroll
    for (int u = 0; u < 4; ++u) {
      float t = q4[u] + k4[u];
      t = fmaxf(t, 0.2f * t);                // leaky_relu(t, 0.2)
      p = __builtin_fmaf(t, a4[u], p);
    }
    // reduce over the 16-lane head group
    p += __shfl_xor(p, 1, 16);
    p += __shfl_xor(p, 2, 16);
    p += __shfl_xor(p, 4, 16);
    p += __shfl_xor(p, 8, 16);
    sc[k] = p;
  }
  float mx = sc[0];
#pragma unroll
  for (int k = 1; k < KNN; ++k) mx = fmaxf(mx, sc[k]);
  float s = 0.f;
#pragma unroll
  for (int k = 0; k < KNN; ++k) {
    sc[k] = __builtin_amdgcn_exp2f((sc[k] - mx) * 1.44269504f);
    s += sc[k];
  }
  const float inv = __builtin_amdgcn_rcpf(s);
  f32x4 acc = {0.f, 0.f, 0.f, 0.f};
#pragma unroll
  for (int k = 0; k < KNN; ++k) {
    const float* vrow = qkvc + (size_t)(bbase + nb[k]) * 768 + 512;
    const f32x4 v4 = *(const f32x4*)&vrow[lane * 4];
    const float wk_ = sc[k] * inv;
#pragma unroll
    for (int u = 0; u < 4; ++u) acc[u] = __builtin_fmaf(wk_, v4[u], acc[u]);
  }
  *(f32x4*)&qkv[(size_t)m * 768 + lane * 4] = acc;   // overwrite own q-slot
}

// ---------------------------------------------------------------- kernel D
// Deterministic two-stage BN stats over qkv's q-slots (stride 768).
__global__ __launch_bounds__(256) void bn_partial_kernel(
    const float* __restrict__ qkv, float* __restrict__ ps,
    float* __restrict__ ps2) {
  const int g = blockIdx.x, c = threadIdx.x;
  float s = 0.f, s2 = 0.f;
  for (int r = 0; r < M_ / 256; ++r) {
    float v = qkv[((size_t)g * (M_ / 256) + r) * 768 + c];
    s += v; s2 += v * v;
  }
  ps[g * 256 + c] = s;
  ps2[g * 256 + c] = s2;
}

__global__ __launch_bounds__(256) void bn_finalize_kernel(
    const float* __restrict__ ps, const float* __restrict__ ps2,
    const float* __restrict__ gamma, const float* __restrict__ beta,
    float* __restrict__ scale, float* __restrict__ shift) {
  const int c = threadIdx.x;
  float s = 0.f, s2 = 0.f;
  for (int g = 0; g < 256; ++g) { s += ps[g * 256 + c]; s2 += ps2[g * 256 + c]; }
  const float mean = s * (1.f / (float)M_);
  const float var = s2 * (1.f / (float)M_) - mean * mean;
  const float rstd = rsqrtf(var + 1e-5f);
  scale[c] = gamma[c] * rstd;
  shift[c] = beta[c] - mean * gamma[c] * rstd;
}

// ---------------------------------------------------------------- kernel E
// y = relu(attn*scale + shift + x), transposed back to [B][C][81] via LDS.
__global__ __launch_bounds__(256) void bn_apply_kernel(
    const float* __restrict__ qkv, const float* __restrict__ x,
    const float* __restrict__ scale, const float* __restrict__ shift,
    float* __restrict__ y) {
  __shared__ float t[N_ * 65];
  const int b = blockIdx.x, tid = threadIdx.x;
  for (int c0 = 0; c0 < 256; c0 += 64) {
    __syncthreads();
    for (int e = tid; e < N_ * 64; e += 256) {
      int n = e >> 6, c = e & 63;
      t[n * 65 + c] = qkv[((size_t)b * N_ + n) * 768 + c0 + c];
    }
    __syncthreads();
    for (int f = tid; f < 64 * N_; f += 256) {
      int c = f / N_, n = f - c * N_;
      float o = t[n * 65 + c];
      size_t gi = (size_t)b * (C_ * N_) + (size_t)(c0 + c) * N_ + n;
      float bn = o * scale[c0 + c] + shift[c0 + c];
      float v = bn + x[gi];
      y[gi] = v > 0.f ? v : 0.f;
    }
  }
}

// ----------------------------------------------------------------
extern "C" void kernel_launch(void* const* d_in, const int* in_sizes, int n_in,
                              void* d_out, int out_size, void* d_ws,
                              size_t ws_size, hipStream_t stream) {
  const float* x     = (const float*)d_in[0];
  const float* wq    = (const float*)d_in[1];
  const float* bq    = (const float*)d_in[2];
  const float* wk    = (const float*)d_in[3];
  const float* bk    = (const float*)d_in[4];
  const float* wv    = (const float*)d_in[5];
  const float* bv    = (const float*)d_in[6];
  const float* a     = (const float*)d_in[7];
  const float* gamma = (const float*)d_in[8];
  const float* beta  = (const float*)d_in[9];
  float* out = (float*)d_out;

  float*  qkv  = (float*)d_ws;                          // M*768 f32
  char*   hlbuf = (char*)qkv;                           // 48 MB, consumed
                                                        // before qkv written
  ushort* tokb = (ushort*)(qkv + (size_t)M_ * 768);     // M*256 bf16
  ushort* wcat = tokb + (size_t)M_ * 256;               // 768*256 bf16
  float*  bcat = (float*)(wcat + 768 * 256);            // 768 f32
  int*    kidx = (int*)(bcat + 768);                    // M*9 int
  float*  ps   = (float*)(kidx + (size_t)M_ * KNN);     // 256*256
  float*  ps2  = ps + 256 * 256;                        // 256*256
  float*  scale = ps2 + 256 * 256;                      // 256
  float*  shift = scale + 256;                          // 256

  split_kernel<<<8 * B_, 256, 0, stream>>>(x, tokb, hlbuf);
  knn_kernel<<<B_, 256, 0, stream>>>(hlbuf, kidx);
  pack_w_kernel<<<768, 256, 0, stream>>>(wq, bq, wk, bk, wv, bv, wcat, bcat);
  qkv_mfma_kernel<<<dim3(M_ / 128, 6), 256, 0, stream>>>(tokb, wcat, bcat, qkv);
  attn_kernel<<<M_ / 4, 256, 0, stream>>>(qkv, kidx, a, qkv);
  bn_partial_kernel<<<256, 256, 0, stream>>>(qkv, ps, ps2);
  bn_finalize_kernel<<<1, 256, 0, stream>>>(ps, ps2, gamma, beta, scale, shift);
  bn_apply_kernel<<<B_, 256, 0, stream>>>(qkv, x, scale, shift, out);
}

// Round 9
// 176.538 us; speedup vs baseline: 1.0932x; 1.0932x over previous
//
#include <hip/hip_runtime.h>
#include <hip/hip_bf16.h>

#define B_   512
#define C_   256
#define N_   81                 // tokens per batch (9x9)
#define M_   (B_ * N_)          // 41472
#define KNN  9

typedef __attribute__((ext_vector_type(8))) short short8;
typedef __attribute__((ext_vector_type(4))) float f32x4;
typedef __attribute__((ext_vector_type(4))) ushort u16x4;

#define GLD16(g, l) __builtin_amdgcn_global_load_lds(                      \
    (const __attribute__((address_space(1))) void*)(g),                    \
    (__attribute__((address_space(3))) void*)(l), 16, 0, 0)

__device__ __forceinline__ float bf2f(ushort u) {
  union { uint i; float f; } c; c.i = (uint)u << 16; return c.f;
}
__device__ __forceinline__ ushort f2bf(float f) {
  __hip_bfloat16 h = __float2bfloat16(f); return *(ushort*)&h;
}

// ---------------------------------------------------------------- kernel A1
// Transpose/split, grid 4096 = (batch, 32-ch chunk). Writes the pre-swizzled
// 12288-B hl image per (b,ch) into hlbuf (rows 81..95 zeroed) + tokb hi rows.
__global__ __launch_bounds__(256) void split_kernel(
    const float* __restrict__ x, ushort* __restrict__ tokb,
    char* __restrict__ hlbuf) {
  __shared__ __align__(16) float raw[32 * 81];   // 10368 B
  const int bid = blockIdx.x;
  const int b = bid >> 3, ch = bid & 7;
  const int tid = threadIdx.x;
  const float* src = x + (size_t)b * (C_ * N_) + ch * 32 * N_;
#pragma unroll
  for (int it = 0; it < 3; ++it) {
    int e4 = tid + it * 256;
    if (e4 < 648) *(f32x4*)&raw[e4 * 4] = *(const f32x4*)&src[e4 * 4];
  }
  char* dst = hlbuf + (size_t)bid * 12288;
  for (int p = tid; p < 480; p += 256)
    *(uint*)(dst + (81 + p / 32) * 128 + (p & 31) * 4) = 0u;
  __syncthreads();
#pragma unroll
  for (int it = 0; it < 6; ++it) {
    int p = tid + it * 256;
    if (p < 1296) {
      int n = p >> 4, q = p & 15;
      float v0 = raw[(2 * q) * N_ + n];
      float v1 = raw[(2 * q + 1) * N_ + n];
      __hip_bfloat16 h0 = __float2bfloat16(v0);
      __hip_bfloat16 h1 = __float2bfloat16(v1);
      float r0 = v0 - __bfloat162float(h0);
      float r1 = v1 - __bfloat162float(h1);
      __hip_bfloat16 g0 = __float2bfloat16(r0);
      __hip_bfloat16 g1 = __float2bfloat16(r1);
      uint hp = (uint)(*(ushort*)&h0) | ((uint)(*(ushort*)&h1) << 16);
      uint lp = (uint)(*(ushort*)&g0) | ((uint)(*(ushort*)&g1) << 16);
      int off = (((q >> 2) << 4) ^ (((n >> 1) & 3) << 4)) + ((q & 3) << 2);
      int hs = (n & 1) << 6;
      *(uint*)(dst + n * 128 + hs + off) = hp;
      *(uint*)(dst + n * 128 + (hs ^ 64) + off) = lp;
      *(uint*)&tokb[((size_t)(b * N_ + n)) * 256 + ch * 32 + 2 * q] = hp;
    }
  }
}

// ---------------------------------------------------------------- kernel A2
// Per batch: stream the 8 pre-swizzled hl chunks via double-buffered
// global_load_lds (counted vmcnt(3)), 4-term MFMA gram, diag from G,
// 9-smallest selection.
__global__ __launch_bounds__(256) void knn_kernel(
    const char* __restrict__ hlbuf, int* __restrict__ knn_idx) {
  __shared__ __align__(16) char smem[31488];     // bufs 2x12288; G overlay
  __shared__ float sqv[96];
  const int b = blockIdx.x;
  const int tid = threadIdx.x;
  const int w = tid >> 6, lane = tid & 63;
  const int wr = w >> 1, wc = w & 1;              // 48x48 quadrant of G
  const int l15 = lane & 15;
  const int g16 = lane >> 4;                      // 16B k-group 0..3

  const char* srcb = hlbuf + (size_t)b * 8 * 12288;

#pragma unroll
  for (int it = 0; it < 3; ++it) {
    int idx = it * 256 + tid;
    GLD16(srcb + idx * 16, smem + idx * 16);
  }

  f32x4 acc[3][3];
#pragma unroll
  for (int i = 0; i < 3; ++i)
#pragma unroll
    for (int j = 0; j < 3; ++j) acc[i][j] = {0.f, 0.f, 0.f, 0.f};

#pragma unroll
  for (int ch = 0; ch < 8; ++ch) {
    char* cur = smem + (ch & 1) * 12288;
    char* nxt = smem + ((ch + 1) & 1) * 12288;
    if (ch < 7) {
      const char* s2 = srcb + (size_t)(ch + 1) * 12288;
#pragma unroll
      for (int it = 0; it < 3; ++it) {
        int idx = it * 256 + tid;
        GLD16(s2 + idx * 16, nxt + idx * 16);
      }
      asm volatile("s_waitcnt vmcnt(3)" ::: "memory");   // cur's 3 done
    } else {
      asm volatile("s_waitcnt vmcnt(0)" ::: "memory");
    }
    __builtin_amdgcn_s_barrier();
    __builtin_amdgcn_sched_barrier(0);
    short8 ah[3], al[3], bh[3], bl[3];
#pragma unroll
    for (int i = 0; i < 3; ++i) {
      int ra = wr * 48 + i * 16 + l15;
      int basea = ra * 128 + ((g16 << 4) ^ (((ra >> 1) & 3) << 4));
      int hsa = (ra & 1) << 6;
      ah[i] = *(const short8*)(cur + basea + hsa);
      al[i] = *(const short8*)(cur + basea + (hsa ^ 64));
      int rb = wc * 48 + i * 16 + l15;
      int baseb = rb * 128 + ((g16 << 4) ^ (((rb >> 1) & 3) << 4));
      int hsb = (rb & 1) << 6;
      bh[i] = *(const short8*)(cur + baseb + hsb);
      bl[i] = *(const short8*)(cur + baseb + (hsb ^ 64));
    }
#pragma unroll
    for (int i = 0; i < 3; ++i)
#pragma unroll
      for (int j = 0; j < 3; ++j) {
        acc[i][j] = __builtin_amdgcn_mfma_f32_16x16x32_bf16(
            ah[i], bh[j], acc[i][j], 0, 0, 0);
        acc[i][j] = __builtin_amdgcn_mfma_f32_16x16x32_bf16(
            ah[i], bl[j], acc[i][j], 0, 0, 0);
        acc[i][j] = __builtin_amdgcn_mfma_f32_16x16x32_bf16(
            al[i], bh[j], acc[i][j], 0, 0, 0);
        acc[i][j] = __builtin_amdgcn_mfma_f32_16x16x32_bf16(
            al[i], bl[j], acc[i][j], 0, 0, 0);
      }
    __builtin_amdgcn_sched_barrier(0);
    __builtin_amdgcn_s_barrier();   // reads done before next GLD overwrite
  }
  float* G = (float*)smem;
#pragma unroll
  for (int i = 0; i < 3; ++i) {
    const int row0 = wr * 48 + i * 16 + ((lane >> 4) << 2);
#pragma unroll
    for (int j = 0; j < 3; ++j) {
      const int col = wc * 48 + j * 16 + l15;
#pragma unroll
      for (int reg = 0; reg < 4; ++reg) {
        const int row = row0 + reg;
        if (row < N_) G[row * 97 + col] = acc[i][j][reg];
      }
    }
  }
  __syncthreads();
  if (tid < N_) sqv[tid] = G[tid * 97 + tid];   // diag = |token|^2 (4-term)
  __syncthreads();
  if (tid < N_) {
    const int n = tid;
    const float sn = sqv[n];
    const float* grow = &G[n * 97];
    float bd[KNN]; int bi[KNN];
#pragma unroll
    for (int k = 0; k < KNN; ++k) { bd[k] = 3.4e38f; bi[k] = 0; }
    for (int m = 0; m < N_; ++m) {
      float d2 = sn + sqv[m] - 2.f * grow[m];
      float wv = bd[0]; int wi = 0;
#pragma unroll
      for (int k = 1; k < KNN; ++k) {
        bool g_ = bd[k] > wv;
        wv = g_ ? bd[k] : wv;
        wi = g_ ? k : wi;
      }
      bool repl = d2 < wv;
#pragma unroll
      for (int k = 0; k < KNN; ++k) {
        bool here = repl & (wi == k);
        bd[k] = here ? d2 : bd[k];
        bi[k] = here ? m : bi[k];
      }
    }
#pragma unroll
    for (int k = 0; k < KNN; ++k)
      knn_idx[((size_t)b * N_ + n) * KNN + k] = bi[k];
  }
}

// ---------------------------------------------------------------- kernel W
__global__ __launch_bounds__(256) void pack_w_kernel(
    const float* __restrict__ wq, const float* __restrict__ bq,
    const float* __restrict__ wk, const float* __restrict__ bk,
    const float* __restrict__ wv, const float* __restrict__ bv,
    ushort* __restrict__ wcat, float* __restrict__ bcat) {
  const int j = blockIdx.x, c = threadIdx.x;
  const int sel = j >> 8, jr = j & 255;
  const float* W  = sel == 0 ? wq : (sel == 1 ? wk : wv);
  const float* Bb = sel == 0 ? bq : (sel == 1 ? bk : bv);
  wcat[(size_t)j * 256 + c] = f2bf(W[jr * 256 + c]);
  if (c == 0) bcat[j] = Bb[jr];
}

// ---------------------------------------------------------------- kernel B
// bf16 MFMA GEMM: qkvb[M][768] (BF16 out) = tok[M][256] @ wcat^T + bcat.
__global__ __launch_bounds__(256) void qkv_mfma_kernel(
    const ushort* __restrict__ tokb, const ushort* __restrict__ wcat,
    const float* __restrict__ bcat, ushort* __restrict__ qkvb) {
  __shared__ ushort At[128 * 64];   // 16 KB, row-major [r][k], swizzled
  __shared__ ushort Bt[128 * 64];   // 16 KB
  const int tid = threadIdx.x;
  const int m0 = blockIdx.x * 128;
  const int j0 = blockIdx.y * 128;
  const int w = tid >> 6, lane = tid & 63;
  const int wr = w >> 1, wc = w & 1;

  const char* pA[4]; const char* pB[4]; int oL[4];
#pragma unroll
  for (int it = 0; it < 4; ++it) {
    int o = (it * 256 + tid) * 16;
    int r = o >> 7, cp = o & 127;
    int cl = cp ^ ((r & 7) << 4);
    oL[it] = o;
    pA[it] = (const char*)tokb + ((size_t)(m0 + r) * 256) * 2 + cl;
    pB[it] = (const char*)wcat + ((size_t)(j0 + r) * 256) * 2 + cl;
  }

  f32x4 acc[4][4];
#pragma unroll
  for (int i = 0; i < 4; ++i)
#pragma unroll
    for (int j = 0; j < 4; ++j) acc[i][j] = {0.f, 0.f, 0.f, 0.f};

  const int l15 = lane & 15;
  const int sw = (lane & 7) << 4;
  const int kgrp = (lane >> 4) << 4;

  for (int k0 = 0; k0 < 256; k0 += 64) {
    __syncthreads();
#pragma unroll
    for (int it = 0; it < 4; ++it) {
      GLD16(pA[it] + k0 * 2, (char*)At + oL[it]);
      GLD16(pB[it] + k0 * 2, (char*)Bt + oL[it]);
    }
    __syncthreads();
#pragma unroll
    for (int kk = 0; kk < 2; ++kk) {
      const int cb = (kk * 64 + kgrp) ^ sw;
      short8 am[4], bn[4];
#pragma unroll
      for (int i = 0; i < 4; ++i) {
        const int ra = wr * 64 + i * 16 + l15;
        am[i] = *(const short8*)((const char*)At + ra * 128 + cb);
        const int rb = wc * 64 + i * 16 + l15;
        bn[i] = *(const short8*)((const char*)Bt + rb * 128 + cb);
      }
#pragma unroll
      for (int i = 0; i < 4; ++i)
#pragma unroll
        for (int j = 0; j < 4; ++j)
          acc[i][j] = __builtin_amdgcn_mfma_f32_16x16x32_bf16(
              am[i], bn[j], acc[i][j], 0, 0, 0);
    }
  }

  // epilogue -> bf16 qkv
#pragma unroll
  for (int j = 0; j < 4; ++j) {
    const int colj = j0 + wc * 64 + j * 16 + l15;
    const float bs = bcat[colj];
#pragma unroll
    for (int i = 0; i < 4; ++i) {
      const int rowm = m0 + wr * 64 + i * 16 + ((lane >> 4) << 2);
#pragma unroll
      for (int reg = 0; reg < 4; ++reg)
        qkvb[(size_t)(rowm + reg) * 768 + colj] = f2bf(acc[i][j][reg] + bs);
    }
  }
}

// ---------------------------------------------------------------- kernel C
// One WAVE per token, bf16 q/k/v (8B per lane loads). Writes bf16 output
// in place into the q-slot of qkvb.
__global__ __launch_bounds__(256) void attn_kernel(
    const ushort* __restrict__ qkvc, const int* __restrict__ knn_idx,
    const float* __restrict__ a, ushort* __restrict__ qkvb) {
  const int nwg = M_ / 4;                    // 10368 = 8 * 1296
  const int bid = blockIdx.x;
  const int swz = (bid & 7) * (nwg / 8) + (bid >> 3);  // XCD-contiguous
  const int w = threadIdx.x >> 6, lane = threadIdx.x & 63;
  const int m = swz * 4 + w;                 // this wave's token
  const int b = m / N_;
  const int bbase = b * N_;

  const u16x4 qu = *(const u16x4*)&qkvc[(size_t)m * 768 + lane * 4];
  const f32x4 a4 = *(const f32x4*)&a[lane * 4];
  float q4[4];
#pragma unroll
  for (int u = 0; u < 4; ++u) q4[u] = bf2f(qu[u]);

  float sc[KNN];
  int nb[KNN];
#pragma unroll
  for (int k = 0; k < KNN; ++k) {
    int nbk = knn_idx[(size_t)m * KNN + k];
    nbk = __builtin_amdgcn_readfirstlane(nbk);
    nb[k] = nbk;
    const ushort* krow = qkvc + (size_t)(bbase + nbk) * 768 + 256;
    const u16x4 ku = *(const u16x4*)&krow[lane * 4];
    float p = 0.f;
#pragma unroll
    for (int u = 0; u < 4; ++u) {
      float t = q4[u] + bf2f(ku[u]);
      t = fmaxf(t, 0.2f * t);                // leaky_relu(t, 0.2)
      p = __builtin_fmaf(t, a4[u], p);
    }
    p += __shfl_xor(p, 1, 16);
    p += __shfl_xor(p, 2, 16);
    p += __shfl_xor(p, 4, 16);
    p += __shfl_xor(p, 8, 16);
    sc[k] = p;
  }
  float mx = sc[0];
#pragma unroll
  for (int k = 1; k < KNN; ++k) mx = fmaxf(mx, sc[k]);
  float s = 0.f;
#pragma unroll
  for (int k = 0; k < KNN; ++k) {
    sc[k] = __builtin_amdgcn_exp2f((sc[k] - mx) * 1.44269504f);
    s += sc[k];
  }
  const float inv = __builtin_amdgcn_rcpf(s);
  f32x4 acc = {0.f, 0.f, 0.f, 0.f};
#pragma unroll
  for (int k = 0; k < KNN; ++k) {
    const ushort* vrow = qkvc + (size_t)(bbase + nb[k]) * 768 + 512;
    const u16x4 vu = *(const u16x4*)&vrow[lane * 4];
    const float wk_ = sc[k] * inv;
#pragma unroll
    for (int u = 0; u < 4; ++u)
      acc[u] = __builtin_fmaf(wk_, bf2f(vu[u]), acc[u]);
  }
  u16x4 o;
#pragma unroll
  for (int u = 0; u < 4; ++u) o[u] = f2bf(acc[u]);
  *(u16x4*)&qkvb[(size_t)m * 768 + lane * 4] = o;   // overwrite own q-slot
}

// ---------------------------------------------------------------- kernel D
// Deterministic two-stage BN stats over bf16 q-slots (stride 768).
__global__ __launch_bounds__(256) void bn_partial_kernel(
    const ushort* __restrict__ qkvb, float* __restrict__ ps,
    float* __restrict__ ps2) {
  const int g = blockIdx.x, c = threadIdx.x;
  float s = 0.f, s2 = 0.f;
  for (int r = 0; r < M_ / 256; ++r) {
    float v = bf2f(qkvb[((size_t)g * (M_ / 256) + r) * 768 + c]);
    s += v; s2 += v * v;
  }
  ps[g * 256 + c] = s;
  ps2[g * 256 + c] = s2;
}

__global__ __launch_bounds__(256) void bn_finalize_kernel(
    const float* __restrict__ ps, const float* __restrict__ ps2,
    const float* __restrict__ gamma, const float* __restrict__ beta,
    float* __restrict__ scale, float* __restrict__ shift) {
  const int c = threadIdx.x;
  float s = 0.f, s2 = 0.f;
  for (int g = 0; g < 256; ++g) { s += ps[g * 256 + c]; s2 += ps2[g * 256 + c]; }
  const float mean = s * (1.f / (float)M_);
  const float var = s2 * (1.f / (float)M_) - mean * mean;
  const float rstd = rsqrtf(var + 1e-5f);
  scale[c] = gamma[c] * rstd;
  shift[c] = beta[c] - mean * gamma[c] * rstd;
}

// ---------------------------------------------------------------- kernel E
// y = relu(attn*scale + shift + x), transposed back to [B][C][81] via LDS.
__global__ __launch_bounds__(256) void bn_apply_kernel(
    const ushort* __restrict__ qkvb, const float* __restrict__ x,
    const float* __restrict__ scale, const float* __restrict__ shift,
    float* __restrict__ y) {
  __shared__ float t[N_ * 65];
  const int b = blockIdx.x, tid = threadIdx.x;
  for (int c0 = 0; c0 < 256; c0 += 64) {
    __syncthreads();
    for (int e = tid; e < N_ * 64; e += 256) {
      int n = e >> 6, c = e & 63;
      t[n * 65 + c] = bf2f(qkvb[((size_t)b * N_ + n) * 768 + c0 + c]);
    }
    __syncthreads();
    for (int f = tid; f < 64 * N_; f += 256) {
      int c = f / N_, n = f - c * N_;
      float o = t[n * 65 + c];
      size_t gi = (size_t)b * (C_ * N_) + (size_t)(c0 + c) * N_ + n;
      float bn = o * scale[c0 + c] + shift[c0 + c];
      float v = bn + x[gi];
      y[gi] = v > 0.f ? v : 0.f;
    }
  }
}

// ----------------------------------------------------------------
extern "C" void kernel_launch(void* const* d_in, const int* in_sizes, int n_in,
                              void* d_out, int out_size, void* d_ws,
                              size_t ws_size, hipStream_t stream) {
  const float* x     = (const float*)d_in[0];
  const float* wq    = (const float*)d_in[1];
  const float* bq    = (const float*)d_in[2];
  const float* wk    = (const float*)d_in[3];
  const float* bk    = (const float*)d_in[4];
  const float* wv    = (const float*)d_in[5];
  const float* bv    = (const float*)d_in[6];
  const float* a     = (const float*)d_in[7];
  const float* gamma = (const float*)d_in[8];
  const float* beta  = (const float*)d_in[9];
  float* out = (float*)d_out;

  ushort* qkvb = (ushort*)d_ws;                         // M*768 bf16 (63.7MB)
  char*   hlbuf = (char*)qkvb;                          // 48 MB alias,
                                                        // consumed pre-qkv
  ushort* tokb = qkvb + (size_t)M_ * 768;               // M*256 bf16
  ushort* wcat = tokb + (size_t)M_ * 256;               // 768*256 bf16
  float*  bcat = (float*)(wcat + 768 * 256);            // 768 f32
  int*    kidx = (int*)(bcat + 768);                    // M*9 int
  float*  ps   = (float*)(kidx + (size_t)M_ * KNN);     // 256*256
  float*  ps2  = ps + 256 * 256;                        // 256*256
  float*  scale = ps2 + 256 * 256;                      // 256
  float*  shift = scale + 256;                          // 256

  split_kernel<<<8 * B_, 256, 0, stream>>>(x, tokb, hlbuf);
  knn_kernel<<<B_, 256, 0, stream>>>(hlbuf, kidx);
  pack_w_kernel<<<768, 256, 0, stream>>>(wq, bq, wk, bk, wv, bv, wcat, bcat);
  qkv_mfma_kernel<<<dim3(M_ / 128, 6), 256, 0, stream>>>(tokb, wcat, bcat, qkvb);
  attn_kernel<<<M_ / 4, 256, 0, stream>>>(qkvb, kidx, a, qkvb);
  bn_partial_kernel<<<256, 256, 0, stream>>>(qkvb, ps, ps2);
  bn_finalize_kernel<<<1, 256, 0, stream>>>(ps, ps2, gamma, beta, scale, shift);
  bn_apply_kernel<<<B_, 256, 0, stream>>>(qkvb, x, scale, shift, out);
}